// Round 4
// baseline (342.670 us; speedup 1.0000x reference)
//
#include <hip/hip_runtime.h>
#include <hip/hip_bf16.h>

#define N_DIM 8192
#define E_DIM 2048
#define NT 64            // K tiles of BK=32
#define BM 128
#define BN 256

typedef __bf16 bf16x8 __attribute__((ext_vector_type(8)));
typedef float  f32x4  __attribute__((ext_vector_type(4)));
typedef short  short8 __attribute__((ext_vector_type(8)));

#define GLD(gp, lp) __builtin_amdgcn_global_load_lds( \
    (const __attribute__((address_space(1))) void*)(gp), \
    (__attribute__((address_space(3))) void*)(lp), 16, 0, 0)

// ---------------- conversion: A fp32 [N,E] -> bf16 [N,E] ----------------
__global__ __launch_bounds__(256) void cvtA(const float* __restrict__ A,
                                            __hip_bfloat16* __restrict__ Abf) {
    size_t i = ((size_t)blockIdx.x * 256 + threadIdx.x) * 8;
    float4 f0 = *reinterpret_cast<const float4*>(A + i);
    float4 f1 = *reinterpret_cast<const float4*>(A + i + 4);
    union { short8 s8; __hip_bfloat16 h[8]; } u;
    u.h[0] = __float2bfloat16(f0.x);
    u.h[1] = __float2bfloat16(f0.y);
    u.h[2] = __float2bfloat16(f0.z);
    u.h[3] = __float2bfloat16(f0.w);
    u.h[4] = __float2bfloat16(f1.x);
    u.h[5] = __float2bfloat16(f1.y);
    u.h[6] = __float2bfloat16(f1.z);
    u.h[7] = __float2bfloat16(f1.w);
    *reinterpret_cast<short8*>(&Abf[i]) = u.s8;
}

// ------- scale+transpose: Bt[n,e] = W[e] * B[e,n], fp32 -> bf16 ---------
__global__ __launch_bounds__(256) void cvtB(const float* __restrict__ B,
                                            const float* __restrict__ W,
                                            __hip_bfloat16* __restrict__ Bt) {
    __shared__ float tile[32][33];
    const int tx = threadIdx.x & 31;
    const int ty = threadIdx.x >> 5;
    const int n0 = blockIdx.x * 32;
    const int e0 = blockIdx.y * 32;
#pragma unroll
    for (int r = 0; r < 4; ++r) {
        int e = e0 + ty + r * 8;
        tile[ty + r * 8][tx] = B[(size_t)e * N_DIM + n0 + tx] * W[e];
    }
    __syncthreads();
#pragma unroll
    for (int r = 0; r < 4; ++r) {
        int n = n0 + ty + r * 8;
        Bt[(size_t)n * E_DIM + e0 + tx] = __float2bfloat16(tile[tx][ty + r * 8]);
    }
}

// ---------------- GEMM: C[N,N] = Abf[N,E] * Btbf[N,E]^T ----------------
// 128x256 tile, BK=32, 8 waves (2Mx4N), 64x64 per wave, depth-2 LDS ring
// (48 KiB/WG -> 2 WGs/CU), one barrier per K-tile, vmcnt(0) drain of loads
// issued a full phase earlier, XOR slot swizzle, setprio, nontemporal C.
__global__ __launch_bounds__(512, 4) void gemm_bt(const __hip_bfloat16* __restrict__ A,
                                                  const __hip_bfloat16* __restrict__ B,
                                                  float* __restrict__ C) {
    __shared__ __align__(16) char lds[49152];
    char* ldsA = (char*)lds;           // 2 x 8192  (128 rows x 64 B)
    char* ldsB = (char*)lds + 16384;   // 2 x 16384 (256 rows x 64 B)

    const int tid  = threadIdx.x;
    const int lane = tid & 63;
    const int wave = tid >> 6;
    const int wm = wave >> 2;          // 0..1  (M half)
    const int wn = wave & 3;           // 0..3  (N quarter)
    const int fr = lane & 15;
    const int sp = (lane >> 4) ^ ((fr >> 1) & 3);   // physical k-slot for ds_read

    // bijective XCD swizzle: 2048 wgs, 256 per XCD (8 tile-rows x 32 cols)
    const int bid = blockIdx.x;
    const int swz = (bid & 7) * 256 + (bid >> 3);
    const int tm = swz >> 5;           // 0..63
    const int tn = swz & 31;           // 0..31

    // staging source pointers (pre-swizzled k-slot, rule 21)
    const int r  = tid >> 2;                        // 0..127
    const int sl = (tid & 3) ^ ((r >> 1) & 3);
    const char* aP  = (const char*)A + ((size_t)(tm * BM + r) * E_DIM + sl * 8) * 2;
    const char* bP0 = (const char*)B + ((size_t)(tn * BN + r) * E_DIM + sl * 8) * 2;
    const char* bP1 = bP0 + (size_t)128 * E_DIM * 2;

    // prologue: stage tile 0 into buf 0
    GLD(aP,  ldsA + wave * 1024);
    GLD(bP0, ldsB + wave * 1024);
    GLD(bP1, ldsB + 8192 + wave * 1024);
    aP += 64; bP0 += 64; bP1 += 64;

    f32x4 acc[4][4] = {};

    for (int kt = 0; kt < NT; ++kt) {
        const int buf = kt & 1;
        asm volatile("s_waitcnt vmcnt(0)" ::: "memory");  // tile kt DMA complete (issued ~1 phase ago)
        __builtin_amdgcn_s_barrier();                     // publish LDS; prior reads retired (MFMA consumed them)
        __builtin_amdgcn_sched_barrier(0);

        if (kt < NT - 1) {  // stage tile kt+1 into buf^1 (issue early, wait next iter)
            char* dA = ldsA + (buf ^ 1) * 8192  + wave * 1024;
            char* dB = ldsB + (buf ^ 1) * 16384 + wave * 1024;
            GLD(aP,  dA);
            GLD(bP0, dB);
            GLD(bP1, dB + 8192);
            aP += 64; bP0 += 64; bP1 += 64;
        }

        const char* At = ldsA + buf * 8192;
        const char* Bt = ldsB + buf * 16384;
        bf16x8 af[4], bf[4];
#pragma unroll
        for (int mi = 0; mi < 4; ++mi)
            af[mi] = *reinterpret_cast<const bf16x8*>(At + (wm * 64 + mi * 16 + fr) * 64 + sp * 16);
#pragma unroll
        for (int ni = 0; ni < 4; ++ni)
            bf[ni] = *reinterpret_cast<const bf16x8*>(Bt + (wn * 64 + ni * 16 + fr) * 64 + sp * 16);

        __builtin_amdgcn_s_setprio(1);
#pragma unroll
        for (int mi = 0; mi < 4; ++mi)
#pragma unroll
            for (int ni = 0; ni < 4; ++ni)
                acc[mi][ni] = __builtin_amdgcn_mfma_f32_16x16x32_bf16(af[mi], bf[ni], acc[mi][ni], 0, 0, 0);
        __builtin_amdgcn_s_setprio(0);
    }

    // epilogue: C/D layout col = lane&15, row = (lane>>4)*4 + j; nontemporal
    const int crow0 = tm * BM + wm * 64 + (lane >> 4) * 4;
    const int ccol0 = tn * BN + wn * 64 + fr;
#pragma unroll
    for (int mi = 0; mi < 4; ++mi)
#pragma unroll
        for (int ni = 0; ni < 4; ++ni)
#pragma unroll
            for (int j = 0; j < 4; ++j)
                __builtin_nontemporal_store(acc[mi][ni][j],
                    &C[(size_t)(crow0 + mi * 16 + j) * N_DIM + (ccol0 + ni * 16)]);
}

extern "C" void kernel_launch(void* const* d_in, const int* in_sizes, int n_in,
                              void* d_out, int out_size, void* d_ws, size_t ws_size,
                              hipStream_t stream) {
    const float* A = (const float*)d_in[0];   // DV2_H        [N, E]
    const float* B = (const float*)d_in[1];   // invDE_HT_DV2 [E, N]
    const float* W = (const float*)d_in[2];   // W            [E]
    float* C = (float*)d_out;                 // G            [N, N] fp32

    __hip_bfloat16* Abf  = (__hip_bfloat16*)d_ws;               // 32 MB
    __hip_bfloat16* Btbf = Abf + (size_t)N_DIM * E_DIM;         // 32 MB

    cvtA<<<(N_DIM * (size_t)E_DIM) / 8 / 256, 256, 0, stream>>>(A, Abf);
    dim3 tgrid(N_DIM / 32, E_DIM / 32);
    cvtB<<<tgrid, 256, 0, stream>>>(B, W, Btbf);
    gemm_bt<<<(N_DIM / BM) * (N_DIM / BN), 512, 0, stream>>>(Abf, Btbf, C);
}

// Round 6
// 308.802 us; speedup vs baseline: 1.1097x; 1.1097x over previous
//
#include <hip/hip_runtime.h>
#include <hip/hip_bf16.h>

#define N_DIM 8192
#define E_DIM 2048
#define NT 64            // K tiles of BK=32

typedef __bf16 bf16x8 __attribute__((ext_vector_type(8)));
typedef float  f32x4  __attribute__((ext_vector_type(4)));
typedef short  short8 __attribute__((ext_vector_type(8)));

#define GLD(gp, lp) __builtin_amdgcn_global_load_lds( \
    (const __attribute__((address_space(1))) void*)(gp), \
    (__attribute__((address_space(3))) void*)(lp), 16, 0, 0)

// ---------------- conversion: A fp32 [N,E] -> bf16 [N,E] ----------------
__global__ __launch_bounds__(256) void cvtA(const float* __restrict__ A,
                                            __hip_bfloat16* __restrict__ Abf) {
    size_t i = ((size_t)blockIdx.x * 256 + threadIdx.x) * 8;
    float4 f0 = *reinterpret_cast<const float4*>(A + i);
    float4 f1 = *reinterpret_cast<const float4*>(A + i + 4);
    union { short8 s8; __hip_bfloat16 h[8]; } u;
    u.h[0] = __float2bfloat16(f0.x);
    u.h[1] = __float2bfloat16(f0.y);
    u.h[2] = __float2bfloat16(f0.z);
    u.h[3] = __float2bfloat16(f0.w);
    u.h[4] = __float2bfloat16(f1.x);
    u.h[5] = __float2bfloat16(f1.y);
    u.h[6] = __float2bfloat16(f1.z);
    u.h[7] = __float2bfloat16(f1.w);
    *reinterpret_cast<short8*>(&Abf[i]) = u.s8;
}

// ------- scale+transpose: Bt[n,e] = W[e] * B[e,n], fp32 -> bf16 ---------
__global__ __launch_bounds__(256) void cvtB(const float* __restrict__ B,
                                            const float* __restrict__ W,
                                            __hip_bfloat16* __restrict__ Bt) {
    __shared__ float tile[32][33];
    const int tx = threadIdx.x & 31;
    const int ty = threadIdx.x >> 5;
    const int n0 = blockIdx.x * 32;
    const int e0 = blockIdx.y * 32;
#pragma unroll
    for (int r = 0; r < 4; ++r) {
        int e = e0 + ty + r * 8;
        tile[ty + r * 8][tx] = B[(size_t)e * N_DIM + n0 + tx] * W[e];
    }
    __syncthreads();
#pragma unroll
    for (int r = 0; r < 4; ++r) {
        int n = n0 + ty + r * 8;
        Bt[(size_t)n * E_DIM + e0 + tx] = __float2bfloat16(tile[tx][ty + r * 8]);
    }
}

// ---------------- GEMM: C[N,N] = Abf[N,E] * Btbf[N,E]^T ----------------
// 256x256 tile, BK=32, 8 waves (2Mx4N, 128x64 each), 4-slot LDS ring,
// one barrier per K-tile, vmcnt(8) (depth-3 prefetch), XOR slot swizzle
// (verified 0 conflicts), setprio; epilogue via LDS transpose + full-line
// nontemporal f32x4 stores (C bypasses caches -> A/B stay resident).

template<bool STG, int VM>
__device__ __forceinline__ void ktile(char* ldsA, char* ldsB, int kt,
    int wm, int wn, int fr, int sp, int wave,
    const char*& aP0, const char*& aP1, const char*& bP0, const char*& bP1,
    f32x4 (&acc)[8][4])
{
    const int buf = kt & 3;
    asm volatile("s_waitcnt vmcnt(%0)" :: "n"(VM) : "memory"); // tile kt DMA done (ours)
    asm volatile("s_waitcnt lgkmcnt(0)" ::: "memory");         // our prior ds_reads retired
    __builtin_amdgcn_s_barrier();                              // all waves: tile kt published
    __builtin_amdgcn_sched_barrier(0);

    if (STG) {  // stage tile kt+3 into ring slot (kt+3)&3
        char* dA = ldsA + ((buf + 3) & 3) * 16384 + wave * 1024;
        char* dB = ldsB + ((buf + 3) & 3) * 16384 + wave * 1024;
        GLD(aP0, dA);
        GLD(aP1, dA + 8192);
        GLD(bP0, dB);
        GLD(bP1, dB + 8192);
        aP0 += 64; aP1 += 64; bP0 += 64; bP1 += 64;
    }

    const char* At = ldsA + buf * 16384;
    const char* Bt = ldsB + buf * 16384;
    bf16x8 af[8], bf[4];
#pragma unroll
    for (int mi = 0; mi < 8; ++mi)
        af[mi] = *reinterpret_cast<const bf16x8*>(At + (wm * 128 + mi * 16 + fr) * 64 + sp * 16);
#pragma unroll
    for (int ni = 0; ni < 4; ++ni)
        bf[ni] = *reinterpret_cast<const bf16x8*>(Bt + (wn * 64 + ni * 16 + fr) * 64 + sp * 16);
    __builtin_amdgcn_sched_barrier(0);

    __builtin_amdgcn_s_setprio(1);
#pragma unroll
    for (int mi = 0; mi < 8; ++mi)
#pragma unroll
        for (int ni = 0; ni < 4; ++ni)
            acc[mi][ni] = __builtin_amdgcn_mfma_f32_16x16x32_bf16(af[mi], bf[ni], acc[mi][ni], 0, 0, 0);
    __builtin_amdgcn_s_setprio(0);
}

__global__ __launch_bounds__(512, 2) void gemm_bt(const __hip_bfloat16* __restrict__ A,
                                                  const __hip_bfloat16* __restrict__ B,
                                                  float* __restrict__ C) {
    __shared__ __align__(16) char lds[131072];
    char* ldsA = (char*)lds;            // 4 slots x 16 KiB
    char* ldsB = (char*)lds + 65536;    // 4 slots x 16 KiB

    const int tid  = threadIdx.x;
    const int lane = tid & 63;
    const int wave = tid >> 6;
    const int wm = wave >> 2;          // 0..1
    const int wn = wave & 3;           // 0..3
    const int fr = lane & 15;
    const int sp = (lane >> 4) ^ ((fr >> 1) & 3);   // physical k-slot (0 conflicts, verified)

    // bijective XCD swizzle: 1024 wgs, 128 per XCD (4 tile-rows x 32 cols)
    const int bid = blockIdx.x;
    const int swz = (bid & 7) * 128 + (bid >> 3);
    const int tm = swz >> 5, tn = swz & 31;

    // staging source pointers (pre-swizzled k-slot, rule 21)
    const char *aP0, *aP1, *bP0, *bP1;
    {
        int g = tid, r = g >> 2, sl = (g & 3) ^ ((r >> 1) & 3);
        aP0 = (const char*)A + ((size_t)(tm * 256 + r) * E_DIM + sl * 8) * 2;
        bP0 = (const char*)B + ((size_t)(tn * 256 + r) * E_DIM + sl * 8) * 2;
        g = tid + 512; r = g >> 2; sl = (g & 3) ^ ((r >> 1) & 3);
        aP1 = (const char*)A + ((size_t)(tm * 256 + r) * E_DIM + sl * 8) * 2;
        bP1 = (const char*)B + ((size_t)(tn * 256 + r) * E_DIM + sl * 8) * 2;
    }

    // prologue: stage tiles 0,1,2 into ring slots 0,1,2 (12 loads in flight)
#pragma unroll
    for (int t = 0; t < 3; ++t) {
        char* dA = ldsA + t * 16384 + wave * 1024;
        char* dB = ldsB + t * 16384 + wave * 1024;
        GLD(aP0, dA);
        GLD(aP1, dA + 8192);
        GLD(bP0, dB);
        GLD(bP1, dB + 8192);
        aP0 += 64; aP1 += 64; bP0 += 64; bP1 += 64;
    }

    f32x4 acc[8][4] = {};

    for (int kt = 0; kt < NT - 3; ++kt)
        ktile<true, 8>(ldsA, ldsB, kt, wm, wn, fr, sp, wave, aP0, aP1, bP0, bP1, acc);
    ktile<false, 8>(ldsA, ldsB, NT - 3, wm, wn, fr, sp, wave, aP0, aP1, bP0, bP1, acc);
    ktile<false, 4>(ldsA, ldsB, NT - 2, wm, wn, fr, sp, wave, aP0, aP1, bP0, bP1, acc);
    ktile<false, 0>(ldsA, ldsB, NT - 1, wm, wn, fr, sp, wave, aP0, aP1, bP0, bP1, acc);

    // ---- epilogue: per 64-row band, transpose through LDS, then stream out
    // full-line nontemporal f32x4 stores (64 threads x 16B = 1 KiB per row).
    float* bandbuf = (float*)lds;      // 64 KiB = 64 rows x 256 cols x 4B
    const int q4 = (lane >> 4) * 4;
#pragma unroll
    for (int b = 0; b < 4; ++b) {
        __syncthreads();               // ring reads done / previous band stores done
        if (wm == (b >> 1)) {
            const int mi0 = (b & 1) * 4;
#pragma unroll
            for (int m = 0; m < 4; ++m)
#pragma unroll
                for (int ni = 0; ni < 4; ++ni)
#pragma unroll
                    for (int j = 0; j < 4; ++j)
                        bandbuf[(m * 16 + q4 + j) * 256 + wn * 64 + ni * 16 + fr] =
                            acc[mi0 + m][ni][j];
        }
        __syncthreads();
        const int rbase = tid >> 6;        // 0..7
        const int c4 = (tid & 63) * 4;     // col in floats
#pragma unroll
        for (int r8 = 0; r8 < 8; ++r8) {
            const int row = r8 * 8 + rbase;
            f32x4 v = *reinterpret_cast<const f32x4*>(&bandbuf[row * 256 + c4]);
            __builtin_nontemporal_store(v, reinterpret_cast<f32x4*>(
                &C[(size_t)(tm * 256 + b * 64 + row) * N_DIM + tn * 256 + c4]));
        }
    }
}

extern "C" void kernel_launch(void* const* d_in, const int* in_sizes, int n_in,
                              void* d_out, int out_size, void* d_ws, size_t ws_size,
                              hipStream_t stream) {
    const float* A = (const float*)d_in[0];   // DV2_H        [N, E]
    const float* B = (const float*)d_in[1];   // invDE_HT_DV2 [E, N]
    const float* W = (const float*)d_in[2];   // W            [E]
    float* C = (float*)d_out;                 // G            [N, N] fp32

    __hip_bfloat16* Abf  = (__hip_bfloat16*)d_ws;               // 32 MB
    __hip_bfloat16* Btbf = Abf + (size_t)N_DIM * E_DIM;         // 32 MB

    cvtA<<<(N_DIM * (size_t)E_DIM) / 8 / 256, 256, 0, stream>>>(A, Abf);
    dim3 tgrid(N_DIM / 32, E_DIM / 32);
    cvtB<<<tgrid, 256, 0, stream>>>(B, W, Btbf);
    gemm_bt<<<(N_DIM / 256) * (N_DIM / 256), 512, 0, stream>>>(Abf, Btbf, C);
}